// Round 2
// baseline (435.421 us; speedup 1.0000x reference)
//
#include <hip/hip_runtime.h>
#include <hip/hip_bf16.h>
#include <cstdint>
#include <cstddef>

// ---------------------------------------------------------------------------
// DatastoreReaderLayer: S=256 B=4 D=512 N=32768, TEMP=0.5
//   q1 = (q @ Wq^T + bq) * D^-0.5
//   Q2 = (q1 @ Wk) * 2 (bf16)     cq = 2*(q1.bk)   [fused into Q2 gemm]
//   E[q,n] = exp(Q2[q,:].k_raw[n,:] + cq[q])
//   racc = E @ V_raw (fp32 atomics), l = rowsum(E)
//   attn = (racc/l) @ Wv^T + bv
//   sdot[r] = relu([attn|prev] @ Wg1^T + bg1) . wg2   [fused epilogue]
//   out = attn*sg + prev*(1-sg), sg = sigmoid(sdot + bg2)
// ---------------------------------------------------------------------------

typedef unsigned short u16;
typedef u16    u16x8 __attribute__((ext_vector_type(8)));
typedef u16    u16x4 __attribute__((ext_vector_type(4)));
typedef __bf16 bf16x8 __attribute__((ext_vector_type(8)));
typedef float  f32x4 __attribute__((ext_vector_type(4)));

#define MFMA16(a, b, c) __builtin_amdgcn_mfma_f32_16x16x32_bf16( \
    __builtin_bit_cast(bf16x8, (a)), __builtin_bit_cast(bf16x8, (b)), (c), 0, 0, 0)

__device__ __forceinline__ u16 f2bf(float f) {  // RNE float->bf16
  unsigned u = __builtin_bit_cast(unsigned, f);
  u += 0x7fffu + ((u >> 16) & 1u);
  return (u16)(u >> 16);
}

// ------------------------- prep: dstore_k -> bf16 ---------------------------
__global__ __launch_bounds__(256) void prep_cvt(const float* __restrict__ src,
                                                u16* __restrict__ dst) {
  size_t i = ((size_t)blockIdx.x * 256 + threadIdx.x) * 4;
  float4 v = *(const float4*)(src + i);
  u16x4 o = {f2bf(v.x), f2bf(v.y), f2bf(v.z), f2bf(v.w)};
  *(u16x4*)(dst + i) = o;
}

// --------------- prep: dstore_v -> bf16 transposed [512][32768] -------------
__global__ __launch_bounds__(256) void prep_vt(const float* __restrict__ v,
                                               u16* __restrict__ vt) {
  __shared__ u16 Lt[64 * 72];  // [d_local][n_local+pad]
  const int n0 = blockIdx.x * 64, d0 = blockIdx.y * 64;
  const int t = threadIdx.x;
  const int n = t >> 2, c4 = t & 3;
#pragma unroll
  for (int i = 0; i < 4; i++) {
    int col = (c4 + 4 * i) * 4;
    float4 x = *(const float4*)(v + (size_t)(n0 + n) * 512 + d0 + col);
    Lt[(col + 0) * 72 + n] = f2bf(x.x);
    Lt[(col + 1) * 72 + n] = f2bf(x.y);
    Lt[(col + 2) * 72 + n] = f2bf(x.z);
    Lt[(col + 3) * 72 + n] = f2bf(x.w);
  }
  __syncthreads();
#pragma unroll
  for (int u = 0; u < 2; u++) {
    int unit = t + 256 * u;
    int d = unit >> 3, un = unit & 7;
    *(u16x8*)(vt + (size_t)(d0 + d) * 32768 + n0 + un * 8) =
        *(const u16x8*)&Lt[d * 72 + un * 8];
  }
}

// --------------- MFMA GEMM, 64x64 tiles, pipelined staging ------------------
// A [1024,KK] fp32 (CONCAT: cols 0..511 from A, 512..1023 from A2, lda=512)
// TRANSB: B [512,KK] use rows;  !TRANSB: B [KK,512]
// CQ (blockIdx.x==0 only): cqout[row] = alpha * (A[row,:] . bkv)
// GATE: no C store; sdot[row] += sum_col relu((acc+bias)*alpha)*wg2[col]
template <bool TRANSB, bool CONCAT, bool RELU, bool OUTBF16, bool ROWSCALE,
          bool CQ, bool GATE, int KK>
__global__ __launch_bounds__(256, 2) void gemm64(
    const float* __restrict__ A, const float* __restrict__ A2,
    const float* __restrict__ B, const float* __restrict__ bias,
    const float* __restrict__ lvec, const float* __restrict__ bkv,
    const float* __restrict__ wg2, float alpha, void* __restrict__ Cv,
    float* __restrict__ cqout, float* __restrict__ sdot) {
  __shared__ u16 As[64 * 72];
  __shared__ u16 Bs[64 * 72];
  const int tid = threadIdx.x;
  const int w = tid >> 6, lane = tid & 63, quad = lane >> 4, l15 = lane & 15;
  const int m0 = blockIdx.y * 64, n0 = blockIdx.x * 64;
  const int arow = tid >> 2, ac4 = tid & 3;
  float rs = 1.0f;
  if (ROWSCALE) rs = 1.0f / lvec[m0 + arow];
  const bool docq = CQ && (blockIdx.x == 0);
  float cqacc = 0.f;
  const f32x4 fzero = {0.f, 0.f, 0.f, 0.f};
  f32x4 acc[4];
#pragma unroll
  for (int i = 0; i < 4; i++) acc[i] = fzero;

  float4 ra[4], rb[4], rk[4];
  auto loadA = [&](int k0) {
    const float* src;
    if (CONCAT)
      src = (k0 < 512) ? (A + (size_t)(m0 + arow) * 512 + k0)
                       : (A2 + (size_t)(m0 + arow) * 512 + (k0 - 512));
    else
      src = A + (size_t)(m0 + arow) * KK + k0;
#pragma unroll
    for (int i = 0; i < 4; i++) ra[i] = *(const float4*)(src + (ac4 + 4 * i) * 4);
  };
  auto loadB = [&](int k0) {
    const float* src = TRANSB ? (B + (size_t)(n0 + arow) * KK + k0)
                              : (B + (size_t)(k0 + arow) * 512 + n0);
#pragma unroll
    for (int i = 0; i < 4; i++) rb[i] = *(const float4*)(src + (ac4 + 4 * i) * 4);
  };
  auto loadK = [&](int k0) {
#pragma unroll
    for (int i = 0; i < 4; i++) rk[i] = *(const float4*)(bkv + k0 + (ac4 + 4 * i) * 4);
  };

  loadA(0); loadB(0);
  if (docq) loadK(0);
#pragma unroll
  for (int k0 = 0; k0 < KK; k0 += 64) {
    __syncthreads();
#pragma unroll
    for (int i = 0; i < 4; i++) {
      int col = (ac4 + 4 * i) * 4;
      float4 x = ra[i];
      if (ROWSCALE) { x.x *= rs; x.y *= rs; x.z *= rs; x.w *= rs; }
      u16x4 oa = {f2bf(x.x), f2bf(x.y), f2bf(x.z), f2bf(x.w)};
      *(u16x4*)&As[arow * 72 + col] = oa;
      float4 y = rb[i];
      if (TRANSB) {
        u16x4 ob = {f2bf(y.x), f2bf(y.y), f2bf(y.z), f2bf(y.w)};
        *(u16x4*)&Bs[arow * 72 + col] = ob;
      } else {
        Bs[(col + 0) * 72 + arow] = f2bf(y.x);
        Bs[(col + 1) * 72 + arow] = f2bf(y.y);
        Bs[(col + 2) * 72 + arow] = f2bf(y.z);
        Bs[(col + 3) * 72 + arow] = f2bf(y.w);
      }
      if (docq)
        cqacc += ra[i].x * rk[i].x + ra[i].y * rk[i].y + ra[i].z * rk[i].z +
                 ra[i].w * rk[i].w;
    }
    if (k0 + 64 < KK) {
      loadA(k0 + 64); loadB(k0 + 64);
      if (docq) loadK(k0 + 64);
    }
    __syncthreads();
#pragma unroll
    for (int ks = 0; ks < 2; ks++) {
      u16x8 af = *(const u16x8*)&As[(w * 16 + l15) * 72 + ks * 32 + quad * 8];
#pragma unroll
      for (int nt = 0; nt < 4; nt++) {
        u16x8 bf = *(const u16x8*)&Bs[(nt * 16 + l15) * 72 + ks * 32 + quad * 8];
        acc[nt] = MFMA16(af, bf, acc[nt]);
      }
    }
  }

  if (docq) {
    cqacc += __shfl_xor(cqacc, 1, 64);
    cqacc += __shfl_xor(cqacc, 2, 64);
    if (ac4 == 0) cqout[m0 + arow] = alpha * cqacc;
  }
  if (GATE) {
    float part[4] = {0.f, 0.f, 0.f, 0.f};
#pragma unroll
    for (int nt = 0; nt < 4; nt++) {
      int col = n0 + nt * 16 + l15;
      float b = bias[col], wv = wg2[col];
#pragma unroll
      for (int i = 0; i < 4; i++) {
        float y = fmaxf((acc[nt][i] + b) * alpha, 0.f);
        part[i] += y * wv;
      }
    }
#pragma unroll
    for (int i = 0; i < 4; i++) {
      float v = part[i];
      v += __shfl_xor(v, 1, 64); v += __shfl_xor(v, 2, 64);
      v += __shfl_xor(v, 4, 64); v += __shfl_xor(v, 8, 64);
      if (l15 == 0) atomicAdd(&sdot[m0 + w * 16 + quad * 4 + i], v);
    }
  } else {
#pragma unroll
    for (int nt = 0; nt < 4; nt++) {
      int col = n0 + nt * 16 + l15;
      float b = bias ? bias[col] : 0.f;
#pragma unroll
      for (int i = 0; i < 4; i++) {
        int row = m0 + w * 16 + quad * 4 + i;
        float y = (acc[nt][i] + b) * alpha;
        if (RELU) y = fmaxf(y, 0.f);
        if (OUTBF16)
          ((u16*)Cv)[(size_t)row * 512 + col] = f2bf(y);
        else
          ((float*)Cv)[(size_t)row * 512 + col] = y;
      }
    }
  }
}

// ------------------------------- flash kernel -------------------------------
// grid 256, XCD-grouped: xcd=bx&7, idx=bx>>3, qt=idx&15, nh2=idx>>4.
// Block rows: xcd*4096 + nh2*2048 (64 subtiles of 32). 8 waves, QT=64.
// 2-barrier pipeline: phase1 = Ks store + K prefetch + PV(sub-1);
//                     phase2 = logits + exp + Es[sub&1] write + V prefetch.
__global__ __launch_bounds__(512, 2) void flash(
    const u16* __restrict__ kbf,  // [32768][512] bf16
    const u16* __restrict__ vt,   // [512][32768] bf16
    const u16* __restrict__ q2,   // [1024][512] bf16
    const float* __restrict__ cq, // [1024]
    float* __restrict__ racc,     // [1024][512] fp32, pre-zeroed
    float* __restrict__ lacc) {   // [1024] fp32, pre-zeroed
  __shared__ u16 Ks[32 * 520];
  __shared__ u16 Es[2][64 * 40];
  const int tid = threadIdx.x;
  const int w = tid >> 6, lane = tid & 63, quad = lane >> 4, l15 = lane & 15;
  const int bx = blockIdx.x;
  const int xcd = bx & 7, idx = bx >> 3;
  const int qt = idx & 15, nh2 = idx >> 4;
  const int rowbase = xcd * 4096 + nh2 * 2048;
  const int qbase = qt * 64;
  const int qg = w >> 1, nh = w & 1;
  const int colb = w * 64;

  u16x8 qf[16];
  {
    const u16* qp = q2 + (size_t)(qbase + qg * 16 + l15) * 512 + quad * 8;
#pragma unroll
    for (int ks = 0; ks < 16; ks++) qf[ks] = *(const u16x8*)(qp + ks * 32);
  }
  float cq4[4];
#pragma unroll
  for (int i = 0; i < 4; i++) cq4[i] = cq[qbase + qg * 16 + quad * 4 + i];
  float lp[4] = {0.f, 0.f, 0.f, 0.f};
  const f32x4 fzero = {0.f, 0.f, 0.f, 0.f};
  f32x4 acc[4][4];
#pragma unroll
  for (int a = 0; a < 4; a++)
#pragma unroll
    for (int b = 0; b < 4; b++) acc[a][b] = fzero;

  u16x8 st[4];   // K staging regs
  u16x8 bvp[4];  // V fragments (loaded in phase2(sub), used in phase1(sub+1))
#pragma unroll
  for (int u = 0; u < 4; u++) {
    int flat = tid + u * 512;
    st[u] = *(const u16x8*)(kbf + (size_t)(rowbase + (flat >> 6)) * 512 + (flat & 63) * 8);
  }

#pragma unroll 1
  for (int sub = 0; sub < 64; ++sub) {
    const int n0 = rowbase + sub * 32;
    __syncthreads();
    // ---- phase1: Ks store, K prefetch, PV for sub-1 ----
#pragma unroll
    for (int u = 0; u < 4; u++) {
      int flat = tid + u * 512;
      *(u16x8*)&Ks[(flat >> 6) * 520 + (flat & 63) * 8] = st[u];
    }
    if (sub + 1 < 64) {
      int n1 = n0 + 32;
#pragma unroll
      for (int u = 0; u < 4; u++) {
        int flat = tid + u * 512;
        st[u] = *(const u16x8*)(kbf + (size_t)(n1 + (flat >> 6)) * 512 + (flat & 63) * 8);
      }
    }
    if (sub > 0) {
      const u16* eb = Es[(sub - 1) & 1];
      u16x8 ef[4];
#pragma unroll
      for (int q2i = 0; q2i < 4; q2i++)
        ef[q2i] = *(const u16x8*)&eb[(q2i * 16 + l15) * 40 + quad * 8];
#pragma unroll
      for (int ct = 0; ct < 4; ct++)
#pragma unroll
        for (int q2i = 0; q2i < 4; q2i++)
          acc[q2i][ct] = MFMA16(ef[q2i], bvp[ct], acc[q2i][ct]);
    }
    __syncthreads();
    // ---- phase2: V prefetch (for next phase1), logits, exp, Es write ----
#pragma unroll
    for (int ct = 0; ct < 4; ct++)
      bvp[ct] = *(const u16x8*)(vt + (size_t)(colb + ct * 16 + l15) * 32768 + n0 + quad * 8);
    f32x4 s = fzero;
#pragma unroll
    for (int ks = 0; ks < 16; ks++) {
      u16x8 bfg = *(const u16x8*)&Ks[(nh * 16 + l15) * 520 + ks * 32 + quad * 8];
      s = MFMA16(qf[ks], bfg, s);
    }
    u16* ew = Es[sub & 1];
#pragma unroll
    for (int i = 0; i < 4; i++) {
      float e = __expf(s[i] + cq4[i]);
      lp[i] += e;
      ew[(qg * 16 + quad * 4 + i) * 40 + nh * 16 + l15] = f2bf(e);
    }
  }
  // ---- final PV for sub=63 ----
  __syncthreads();
  {
    const u16* eb = Es[1];
    u16x8 ef[4];
#pragma unroll
    for (int q2i = 0; q2i < 4; q2i++)
      ef[q2i] = *(const u16x8*)&eb[(q2i * 16 + l15) * 40 + quad * 8];
#pragma unroll
    for (int ct = 0; ct < 4; ct++)
#pragma unroll
      for (int q2i = 0; q2i < 4; q2i++)
        acc[q2i][ct] = MFMA16(ef[q2i], bvp[ct], acc[q2i][ct]);
  }
  // ---- combine partials ----
#pragma unroll
  for (int q2i = 0; q2i < 4; q2i++)
#pragma unroll
    for (int ct = 0; ct < 4; ct++) {
      int col = colb + ct * 16 + l15;
#pragma unroll
      for (int i = 0; i < 4; i++) {
        int row = qbase + q2i * 16 + quad * 4 + i;
        atomicAdd(&racc[(size_t)row * 512 + col], acc[q2i][ct][i]);
      }
    }
#pragma unroll
  for (int i = 0; i < 4; i++) {
    float v = lp[i];
#pragma unroll
    for (int off = 1; off < 16; off <<= 1) v += __shfl_xor(v, off, 64);
    if (l15 == 0) atomicAdd(&lacc[qbase + qg * 16 + quad * 4 + i], v);
  }
}

// ----------------------- finalize: sigma gate + mix -------------------------
__global__ __launch_bounds__(128) void finalize(
    const float* __restrict__ sdot, const float* __restrict__ bg2,
    const float* __restrict__ attn, const float* __restrict__ prev,
    float* __restrict__ out) {
  int r = blockIdx.x, t = threadIdx.x;
  float sg = 1.f / (1.f + __expf(-(sdot[r] + bg2[0])));
  float4 a = ((const float4*)(attn + (size_t)r * 512))[t];
  float4 p = ((const float4*)(prev + (size_t)r * 512))[t];
  float4 o = {a.x * sg + p.x * (1.f - sg), a.y * sg + p.y * (1.f - sg),
              a.z * sg + p.z * (1.f - sg), a.w * sg + p.w * (1.f - sg)};
  ((float4*)(out + (size_t)r * 512))[t] = o;
}

// ---------------------------------------------------------------------------
extern "C" void kernel_launch(void* const* d_in, const int* in_sizes, int n_in,
                              void* d_out, int out_size, void* d_ws, size_t ws_size,
                              hipStream_t stream) {
  const float* q    = (const float*)d_in[0];
  const float* prev = (const float*)d_in[1];
  const float* Wq   = (const float*)d_in[2];
  const float* bq   = (const float*)d_in[3];
  const float* Wk   = (const float*)d_in[4];
  const float* bk   = (const float*)d_in[5];
  const float* Wv   = (const float*)d_in[6];
  const float* bv   = (const float*)d_in[7];
  const float* Wg1  = (const float*)d_in[8];
  const float* bg1  = (const float*)d_in[9];
  const float* Wg2  = (const float*)d_in[10];
  const float* bg2  = (const float*)d_in[11];
  const float* dk   = (const float*)d_in[12];
  const float* dv   = (const float*)d_in[13];
  float* out = (float*)d_out;

  char* ws = (char*)d_ws;
  u16*   kbf  = (u16*)(ws);                  // 33,554,432
  u16*   vt   = (u16*)(ws + 33554432);       // 33,554,432
  float* racc = (float*)(ws + 67108864);     // 2 MB
  float* lacc = (float*)(ws + 69206016);     // 4 KB
  float* sdot = (float*)(ws + 69210112);     // 4 KB
  float* cqv  = (float*)(ws + 69214208);     // 4 KB
  u16*   q2   = (u16*)(ws + 69218304);       // 1 MB
  float* q1   = (float*)(ws + 70266880);     // 2 MB
  float* attn = (float*)(ws + 72364032);     // 2 MB  -> total 74,461,184 B

  prep_cvt<<<16384, 256, 0, stream>>>(dk, kbf);
  prep_vt<<<dim3(512, 8), 256, 0, stream>>>(dv, vt);
  // q1 = (q @ Wq^T + bq) * D^-0.5
  gemm64<true, false, false, false, false, false, false, 512>
      <<<dim3(8, 16), 256, 0, stream>>>(q, nullptr, Wq, bq, nullptr, nullptr,
                                        nullptr, 0.044194173824159216f, q1,
                                        nullptr, nullptr);
  // Q2 = (q1 @ Wk) * 2 (bf16), fused cq = 2*(q1.bk)
  gemm64<false, false, false, true, false, true, false, 512>
      <<<dim3(8, 16), 256, 0, stream>>>(q1, nullptr, Wk, nullptr, nullptr, bk,
                                        nullptr, 2.0f, q2, cqv, nullptr);
  hipMemsetAsync(racc, 0, 2105344, stream);  // racc + lacc + sdot
  flash<<<256, 512, 0, stream>>>(kbf, vt, q2, cqv, racc, lacc);
  // attn = (racc/l) @ Wv^T + bv
  gemm64<true, false, false, false, true, false, false, 512>
      <<<dim3(8, 16), 256, 0, stream>>>(racc, nullptr, Wv, bv, lacc, nullptr,
                                        nullptr, 1.0f, attn, nullptr, nullptr);
  // sdot = relu([attn|prev] @ Wg1^T + bg1) . wg2
  gemm64<true, true, true, false, false, false, true, 1024>
      <<<dim3(8, 16), 256, 0, stream>>>(attn, prev, Wg1, bg1, nullptr, nullptr,
                                        Wg2, 1.0f, nullptr, nullptr, sdot);
  finalize<<<1024, 128, 0, stream>>>(sdot, bg2, attn, prev, out);
}